// Round 9
// baseline (350.962 us; speedup 1.0000x reference)
//
#include <hip/hip_runtime.h>
#include <hip/hip_bf16.h>
#include <math.h>

#define BB 8
#define CH 64
#define NP 4096
#define RG 32
#define R3 32768
#define PD 34
#define PD2 1156
#define PCELLS 39304
#define LEAK 0.2f
#define BNEPS 1e-5f
#define GNEPS 1e-5f

typedef short short8 __attribute__((ext_vector_type(8)));
typedef float float4_ __attribute__((ext_vector_type(4)));

__device__ __forceinline__ short f2bf(float f){
  unsigned u = __float_as_uint(f);
  u += 0x7FFF + ((u>>16)&1);          // RNE
  return (short)(u>>16);
}
__device__ __forceinline__ float bf2f(short s){
  unsigned u = ((unsigned)(unsigned short)s)<<16;
  return __uint_as_float(u);
}

__device__ __forceinline__ void gload_lds16(const short* src, short* dst){
#if __has_builtin(__builtin_amdgcn_global_load_lds)
  __builtin_amdgcn_global_load_lds(
    (const __attribute__((address_space(1))) void*)src,
    (__attribute__((address_space(3))) void*)dst, 16, 0, 0);
#else
  *(short8*)dst = *(const short8*)src;
#endif
}

// ---------------- voxelize stats ----------------
__global__ void k_voxstats(const float* __restrict__ coords, float* __restrict__ ms){
  int b = blockIdx.x;
  __shared__ float red[256];
  float mean[3];
  for(int d=0; d<3; d++){
    float s=0.f;
    for(int i=threadIdx.x; i<NP; i+=256) s += coords[(b*3+d)*NP+i];
    red[threadIdx.x]=s; __syncthreads();
    for(int o=128;o>0;o>>=1){ if(threadIdx.x<o) red[threadIdx.x]+=red[threadIdx.x+o]; __syncthreads(); }
    mean[d]=red[0]/(float)NP; __syncthreads();
  }
  float mx=0.f;
  for(int i=threadIdx.x; i<NP; i+=256){
    float x=coords[(b*3+0)*NP+i]-mean[0];
    float y=coords[(b*3+1)*NP+i]-mean[1];
    float z=coords[(b*3+2)*NP+i]-mean[2];
    mx=fmaxf(mx, sqrtf(x*x+y*y+z*z));
  }
  red[threadIdx.x]=mx; __syncthreads();
  for(int o=128;o>0;o>>=1){ if(threadIdx.x<o) red[threadIdx.x]=fmaxf(red[threadIdx.x],red[threadIdx.x+o]); __syncthreads(); }
  if(threadIdx.x==0){
    ms[b*4+0]=mean[0]; ms[b*4+1]=mean[1]; ms[b*4+2]=mean[2];
    ms[b*4+3]=red[0]*2.0f;
  }
}

// ---------------- norm coords + voxel index ----------------
__global__ void k_assign(const float* __restrict__ coords, const float* __restrict__ ms,
                         float* __restrict__ nc, int* __restrict__ vi){
  int t = blockIdx.x*256+threadIdx.x;
  if(t>=BB*NP) return;
  int b=t/NP, n=t-b*NP;
  float scale=ms[b*4+3];
  int vox[3];
  #pragma unroll
  for(int d=0; d<3; d++){
    float c=coords[(b*3+d)*NP+n] - ms[b*4+d];
    float v=(c/scale + 0.5f)*32.0f;
    v=fminf(fmaxf(v,0.0f),31.0f);
    nc[(b*3+d)*NP+n]=v;
    vox[d]=(int)rintf(v);
  }
  vi[t]=vox[0]*1024+vox[1]*32+vox[2];
}

// --------- scatter: one wave per point, lane = channel ----------
__global__ void k_scatter(const float* __restrict__ feat, const int* __restrict__ vi,
                          float* __restrict__ gsum, float* __restrict__ cnt){
  int wid = (blockIdx.x*256+threadIdx.x)>>6;
  int lane = threadIdx.x&63;
  if(wid>=BB*NP) return;
  int b=wid>>12, n=wid&4095;
  int idx=vi[wid];
  float f = feat[((size_t)(b*CH+lane))*NP + n];
  atomicAdd(gsum + ((size_t)b*R3+idx)*CH + lane, f);
  if(lane==0) atomicAdd(&cnt[b*R3+idx], 1.0f);
}

// ------- sums -> means, f32 -> bf16, write into PADDED grid -------
__global__ void k_gridmean(const float* __restrict__ gsum, const float* __restrict__ cnt,
                           short* __restrict__ gpad){
  int t=blockIdx.x*256+threadIdx.x;
  if(t>=BB*R3*8) return;
  int v=t>>3, q=t&7;
  float inv=1.0f/fmaxf(cnt[v],1.0f);
  const float* sp=gsum + (size_t)v*CH + q*8;
  short8 o;
  #pragma unroll
  for(int j=0;j<8;j++) o[j]=f2bf(sp[j]*inv);
  int b=v>>15, r=v&32767;
  int z=r>>10, y=(r>>5)&31, x=r&31;
  size_t pc=(size_t)b*PCELLS + (z+1)*PD2 + (y+1)*PD + (x+1);
  ((short8*)gpad)[pc*8+q]=o;
}

// ------- weights: w[oc][ci][tap] -> per-fragment contiguous bf16 -------
__global__ void k_wt3(const float* __restrict__ w, short* __restrict__ wt3){
  int t=blockIdx.x*256+threadIdx.x;
  if(t>=CH*CH*27) return;
  int frag=t>>9, l=(t>>3)&63, j=t&7;
  int tap=frag>>3, hh=(frag>>2)&1, nf=frag&3;
  int oc=nf*16+(l&15);
  int ci=hh*32+(l>>4)*8+j;
  wt3[t]=f2bf(w[oc*1728 + ci*27 + tap]);
}

// ------------- MFMA implicit-GEMM 3x3x3 conv + bias + BN + leaky -------------
// gin: PADDED [b][34^3][ci] bf16. gout: cell = (z+po)*s1 + (y+po)*s2 + (x+po).
// tile 4z x 8y x 8x, 4 waves (wave=z-layer), ci in 2 halves of 32.
// LDS: linear [cell 0..599][4 cb-slots] short8; slot = cell*4 + (cb^(cell&3)).
__global__ __launch_bounds__(256,3) void k_conv_mfma(
    const short* __restrict__ gin, short* __restrict__ gout,
    const short* __restrict__ wt3, const float* __restrict__ bias,
    const float* __restrict__ bg, const float* __restrict__ bb,
    const float* __restrict__ bm, const float* __restrict__ bv,
    int po, int s1, int s2){
  __shared__ __align__(16) short in_s[2432*8];   // 38912 B (2400 units + DMA pad)
  int tid=threadIdx.x;
  int blk=blockIdx.x;                 // 8b x 8zt x 4yt x 4xt = 1024
  int b=blk>>7, zt=(blk>>4)&7, yt=(blk>>2)&3, xt=blk&3;
  int z0=zt*4, y0=yt*8, x0=xt*8;
  const short* gbase = gin + (size_t)b*PCELLS*CH;

  int lane=tid&63, zl=tid>>6;
  int r15=lane&15, g=lane>>4;
  int ix=r15&7, iyq=r15>>3;

  float4_ acc[4][4];
  #pragma unroll
  for(int mf=0;mf<4;mf++)
    #pragma unroll
    for(int nf=0;nf<4;nf++) acc[mf][nf]=(float4_){0.f,0.f,0.f,0.f};

  short8* s8=(short8*)in_s;

  for(int hh=0; hh<2; hh++){
    __syncthreads();
    // ---- async DMA stage: 6z x 10y x 10x cells, 32 ci (4 cb of 8) ----
    // unit u = cell*4 + s; LDS linear at u*16B; source cb = s ^ (cell&3)
    for(int ub=zl*64; ub<2400; ub+=256){
      int u=ub+lane;
      int cell=u>>2; cell = cell>599 ? 599 : cell;
      int s=u&3;
      int cb=s^(cell&3);
      int z=cell/100; int r=cell-z*100; int y=r/10; int x=r-y*10;
      const short* src = gbase + ((size_t)((z0+z)*PD2 + (y0+y)*PD + (x0+x)))*CH + hh*32 + cb*8;
      gload_lds16(src, in_s + (size_t)ub*8);
    }
    __syncthreads();

    const short8* wb = ((const short8*)wt3) + hh*256 + lane;
    short8 bw0[4], bw1[4], aA[4], aB[4];
    #pragma unroll
    for(int nf=0;nf<4;nf++) bw0[nf]=wb[nf*64];
    #pragma unroll
    for(int nf=0;nf<4;nf++) bw1[nf]=wb[512+nf*64];
    // preload A for tap 0
    #pragma unroll
    for(int mf=0;mf<4;mf++){
      int cell=zl*100 + (iyq+mf*2)*10 + ix;
      aA[mf]=s8[cell*4 + (g^(cell&3))];
    }

    for(int tt=0; tt<27; tt+=2){
      {
        if(tt+1<27){
          int t1=tt+1, kz=t1/9, r=t1-kz*9, ky=r/3, kx=r-ky*3;
          #pragma unroll
          for(int mf=0;mf<4;mf++){
            int cell=(zl+kz)*100+(iyq+mf*2+ky)*10+ix+kx;
            aB[mf]=s8[cell*4 + (g^(cell&3))];
          }
        }
        #pragma unroll
        for(int mf=0;mf<4;mf++)
          #pragma unroll
          for(int nf=0;nf<4;nf++)
            acc[mf][nf]=__builtin_amdgcn_mfma_f32_16x16x32_bf16(aA[mf],bw0[nf],acc[mf][nf],0,0,0);
        if(tt+2<27){
          #pragma unroll
          for(int nf=0;nf<4;nf++) bw0[nf]=wb[(tt+2)*512+nf*64];
        }
      }
      if(tt+1<27){
        if(tt+2<27){
          int t2=tt+2, kz=t2/9, r=t2-kz*9, ky=r/3, kx=r-ky*3;
          #pragma unroll
          for(int mf=0;mf<4;mf++){
            int cell=(zl+kz)*100+(iyq+mf*2+ky)*10+ix+kx;
            aA[mf]=s8[cell*4 + (g^(cell&3))];
          }
        }
        #pragma unroll
        for(int mf=0;mf<4;mf++)
          #pragma unroll
          for(int nf=0;nf<4;nf++)
            acc[mf][nf]=__builtin_amdgcn_mfma_f32_16x16x32_bf16(aB[mf],bw1[nf],acc[mf][nf],0,0,0);
        if(tt+3<27){
          #pragma unroll
          for(int nf=0;nf<4;nf++) bw1[nf]=wb[(tt+3)*512+nf*64];
        }
      }
    }
  }

  // ---- epilogue: bias + BN + leaky -> LDS bf16 repack -> coalesced stores ----
  __syncthreads();
  short* ot=(short*)in_s;             // [256 rows][stride 72] = 36864 B
  #pragma unroll
  for(int nf=0;nf<4;nf++){
    int oc=nf*16+r15;
    float iv=bg[oc]/sqrtf(bv[oc]+BNEPS);
    float sh=bias[oc]*iv + bb[oc]-bm[oc]*iv;
    #pragma unroll
    for(int mf=0;mf<4;mf++){
      #pragma unroll
      for(int q=0;q<4;q++){
        int row=mf*16+g*4+q;
        float val=acc[mf][nf][q]*iv+sh;
        val = val>=0.f ? val : LEAK*val;
        ot[(zl*64+row)*72 + oc]=f2bf(val);
      }
    }
  }
  __syncthreads();
  short* go = gout + (size_t)b*((size_t)(s1==PD2? PCELLS : R3))*CH;
  for(int e=tid; e<2048; e+=256){
    int vr=e>>3, j=e&7;
    int zz=vr>>6, rr=vr&63;
    short8 v=*(short8*)(ot + vr*72 + j*8);
    size_t cell = (size_t)(z0+zz+po)*s1 + (size_t)(y0+(rr>>3)+po)*s2 + (x0+(rr&7)+po);
    *(short8*)(go + cell*CH + j*8)=v;
  }
}

// ------- point MLP + fused GN partial stats -------
__global__ __launch_bounds__(256,2) void k_ptgemm(
    const float* __restrict__ feat, const float* __restrict__ w,
    const float* __restrict__ bias, float* __restrict__ y,
    float* __restrict__ stp){
  __shared__ float ws_[64*64];
  __shared__ float ft[64][65];
  __shared__ float sg[8], qg[8];
  int tid=threadIdx.x;
  int blk=blockIdx.x;
  int b=blk>>6, n0=(blk&63)*64;
  for(int e=tid;e<4096;e+=256) ws_[e]=w[e];
  for(int e=tid;e<4096;e+=256){
    int c=e>>6, nl=e&63;
    ft[c][nl]=feat[(size_t)(b*CH+c)*NP + n0+nl];
  }
  if(tid<8){ sg[tid]=0.f; qg[tid]=0.f; }
  __syncthreads();
  int nl=tid&63, qq=tid>>6;
  float ps[2]={0.f,0.f}, pq[2]={0.f,0.f};
  #pragma unroll
  for(int j=0;j<16;j++){
    int o=qq*16+j;
    float a=bias[o];
    #pragma unroll
    for(int c=0;c<64;c++) a=fmaf(ws_[o*64+c], ft[c][nl], a);
    y[(size_t)(b*CH+o)*NP+n0+nl]=a;
    int gi=j>>3;
    ps[gi]+=a; pq[gi]+=a*a;
  }
  #pragma unroll
  for(int off=32;off>0;off>>=1){
    ps[0]+=__shfl_down(ps[0],off,64); pq[0]+=__shfl_down(pq[0],off,64);
    ps[1]+=__shfl_down(ps[1],off,64); pq[1]+=__shfl_down(pq[1],off,64);
  }
  if((tid&63)==0){
    atomicAdd(&sg[qq*2+0],ps[0]); atomicAdd(&qg[qq*2+0],pq[0]);
    atomicAdd(&sg[qq*2+1],ps[1]); atomicAdd(&qg[qq*2+1],pq[1]);
  }
  __syncthreads();
  if(tid<8){
    atomicAdd(&stp[(b*8+tid)*2+0], sg[tid]);
    atomicAdd(&stp[(b*8+tid)*2+1], qg[tid]);
  }
}

// ---------------- finalize GN stats ----------------
__global__ void k_gnfinal(const float* __restrict__ stp, float* __restrict__ st){
  int t=threadIdx.x;
  if(t>=64) return;
  float s=stp[t*2+0], q=stp[t*2+1];
  float mu=s/(8.f*NP);
  float var=q/(8.f*NP)-mu*mu;
  st[t*2+0]=mu;
  st[t*2+1]=1.0f/sqrtf(var+GNEPS);
}

// ------- devoxelize + GN affine + swish + add; LDS-transposed coalesced out -------
__global__ void k_fuse(const short* __restrict__ grid, const float* __restrict__ nc,
                       const float* __restrict__ py, const float* __restrict__ st,
                       const float* __restrict__ gg, const float* __restrict__ gb,
                       float* __restrict__ out){
  __shared__ float ot[64][65];
  int tid=threadIdx.x;
  int blk=blockIdx.x;
  int b=blk>>6, n0=(blk&63)*64;
  int nl=tid>>2, qq=tid&3;
  int n=n0+nl;

  float d_[3]; int i0[3], i1[3];
  #pragma unroll
  for(int dd=0;dd<3;dd++){
    float c=nc[(b*3+dd)*NP+n];
    c=fminf(fmaxf(c,0.f),31.f);
    float f=floorf(c);
    d_[dd]=c-f;
    i0[dd]=(int)f;
    i1[dd]=min(i0[dd]+1,31);
  }
  int idx8[8]; float w8[8];
  #pragma unroll
  for(int k=0;k<8;k++){
    int xx=(k&4)?i1[0]:i0[0];
    int yy=(k&2)?i1[1]:i0[1];
    int zz=(k&1)?i1[2]:i0[2];
    float wx=(k&4)?d_[0]:(1.f-d_[0]);
    float wy=(k&2)?d_[1]:(1.f-d_[1]);
    float wz=(k&1)?d_[2]:(1.f-d_[2]);
    idx8[k]=xx*1024+yy*32+zz;
    w8[k]=wx*wy*wz;
  }
  const short* gbase = grid + (size_t)b*R3*CH;
  #pragma unroll
  for(int c8=0;c8<2;c8++){
    int c0=qq*16+c8*8;
    float dv[8]={0.f,0.f,0.f,0.f,0.f,0.f,0.f,0.f};
    #pragma unroll
    for(int k=0;k<8;k++){
      short8 gv=*(const short8*)(gbase + (size_t)idx8[k]*CH + c0);
      #pragma unroll
      for(int j=0;j<8;j++) dv[j]+=w8[k]*bf2f(gv[j]);
    }
    #pragma unroll
    for(int j=0;j<8;j++){
      int c=c0+j;
      float mu  =st[(b*8+(c>>3))*2+0];
      float rstd=st[(b*8+(c>>3))*2+1];
      float yn=(py[(size_t)(b*CH+c)*NP+n]-mu)*rstd*gg[c]+gb[c];
      float sw=yn/(1.f+expf(-yn));
      ot[c][nl]=dv[j]+sw;
    }
  }
  __syncthreads();
  for(int i=tid;i<1024;i+=256){
    int c=i>>4, sg=i&15;
    float4_ v={ot[c][sg*4+0],ot[c][sg*4+1],ot[c][sg*4+2],ot[c][sg*4+3]};
    *(float4_*)(out + (size_t)(b*CH+c)*NP + n0 + sg*4) = v;
  }
}

// ---------------- passthrough copy ----------------
__global__ void k_copy(const float* __restrict__ src, float* __restrict__ dst, int n){
  int t=blockIdx.x*256+threadIdx.x;
  if(t<n) dst[t]=src[t];
}

extern "C" void kernel_launch(void* const* d_in, const int* in_sizes, int n_in,
                              void* d_out, int out_size, void* d_ws, size_t ws_size,
                              hipStream_t stream){
  const float* features=(const float*)d_in[0];
  const float* coords  =(const float*)d_in[1];
  const float* temb    =(const float*)d_in[2];
  const float* c1w=(const float*)d_in[3];
  const float* c1b=(const float*)d_in[4];
  const float* b1g=(const float*)d_in[5];
  const float* b1b=(const float*)d_in[6];
  const float* b1m=(const float*)d_in[7];
  const float* b1v=(const float*)d_in[8];
  const float* c2w=(const float*)d_in[9];
  const float* c2b=(const float*)d_in[10];
  const float* b2g=(const float*)d_in[11];
  const float* b2b=(const float*)d_in[12];
  const float* b2m=(const float*)d_in[13];
  const float* b2v=(const float*)d_in[14];
  const float* pfw=(const float*)d_in[15];
  const float* pfb=(const float*)d_in[16];
  const float* gng=(const float*)d_in[17];
  const float* gnb=(const float*)d_in[18];

  float* F=(float*)d_ws;
  float* ms  = F + 0;                   // 32
  float* nc  = F + 32;                  // 98304
  int*   vi  = (int*)(F + 98336);       // 32768
  short* w1t = (short*)(F + 131104);    // 110592 sh
  short* w2t = (short*)(F + 186400);    // 110592 sh
  float* py  = F + 241696;              // 2097152
  float* st  = F + 2338848;             // 128
  float* stp = F + 2338976;             // 128  (memset start)
  float* cnt = F + 2339104;             // 262144
  float* gA  = F + 2601248;             // 16777216 (scatter sums; later gP2+gOut)
  short* gP2 = (short*)gA;              //   padded conv1-out: 20123648 sh = 10061824 f
  short* gOut= (short*)(F + 2601248 + 10061824); // 16777216 sh = 8388608 f
  short* gP1 = (short*)(F + 19378464);  // padded grid: 10061824 f
  float* out=(float*)d_out;

  // zero: stp + cnt + gA(67MB) + gP1(40MB)
  hipMemsetAsync(stp, 0, (size_t)(128+262144+16777216+10061824)*4, stream);

  k_voxstats<<<8,256,0,stream>>>(coords, ms);
  k_assign  <<<128,256,0,stream>>>(coords, ms, nc, vi);
  k_scatter <<<8192,256,0,stream>>>(features, vi, gA, cnt);
  k_gridmean<<<8192,256,0,stream>>>(gA, cnt, gP1);
  // gA is dead now; zero gP2 (aliases gA) so its pad borders are true zeros
  hipMemsetAsync(gP2, 0, (size_t)20123648*2, stream);
  k_wt3     <<<432,256,0,stream>>>(c1w, w1t);
  k_wt3     <<<432,256,0,stream>>>(c2w, w2t);
  k_conv_mfma<<<1024,256,0,stream>>>(gP1, gP2, w1t, c1b, b1g, b1b, b1m, b1v, 1, PD2, PD);
  k_conv_mfma<<<1024,256,0,stream>>>(gP2, gOut, w2t, c2b, b2g, b2b, b2m, b2v, 0, 1024, 32);
  k_ptgemm  <<<512,256,0,stream>>>(features, pfw, pfb, py, stp);
  k_gnfinal <<<1,64,0,stream>>>(stp, st);
  k_fuse    <<<512,256,0,stream>>>(gOut, nc, py, st, gng, gnb, out);
  k_copy    <<<(98304+255)/256,256,0,stream>>>(coords, out+2097152, 98304);
  k_copy    <<<2,256,0,stream>>>(temb, out+2195456, 512);
}

// Round 10
// 266.707 us; speedup vs baseline: 1.3159x; 1.3159x over previous
//
#include <hip/hip_runtime.h>
#include <hip/hip_bf16.h>
#include <math.h>

#define BB 8
#define CH 64
#define NP 4096
#define RG 32
#define R3 32768
#define LEAK 0.2f
#define BNEPS 1e-5f
#define GNEPS 1e-5f

typedef short short8 __attribute__((ext_vector_type(8)));
typedef float float4_ __attribute__((ext_vector_type(4)));

__device__ __forceinline__ short f2bf(float f){
  unsigned u = __float_as_uint(f);
  u += 0x7FFF + ((u>>16)&1);          // RNE
  return (short)(u>>16);
}
__device__ __forceinline__ float bf2f(short s){
  unsigned u = ((unsigned)(unsigned short)s)<<16;
  return __uint_as_float(u);
}

// ---------------- voxelize stats ----------------
__global__ void k_voxstats(const float* __restrict__ coords, float* __restrict__ ms){
  int b = blockIdx.x;
  __shared__ float red[256];
  float mean[3];
  for(int d=0; d<3; d++){
    float s=0.f;
    for(int i=threadIdx.x; i<NP; i+=256) s += coords[(b*3+d)*NP+i];
    red[threadIdx.x]=s; __syncthreads();
    for(int o=128;o>0;o>>=1){ if(threadIdx.x<o) red[threadIdx.x]+=red[threadIdx.x+o]; __syncthreads(); }
    mean[d]=red[0]/(float)NP; __syncthreads();
  }
  float mx=0.f;
  for(int i=threadIdx.x; i<NP; i+=256){
    float x=coords[(b*3+0)*NP+i]-mean[0];
    float y=coords[(b*3+1)*NP+i]-mean[1];
    float z=coords[(b*3+2)*NP+i]-mean[2];
    mx=fmaxf(mx, sqrtf(x*x+y*y+z*z));
  }
  red[threadIdx.x]=mx; __syncthreads();
  for(int o=128;o>0;o>>=1){ if(threadIdx.x<o) red[threadIdx.x]=fmaxf(red[threadIdx.x],red[threadIdx.x+o]); __syncthreads(); }
  if(threadIdx.x==0){
    ms[b*4+0]=mean[0]; ms[b*4+1]=mean[1]; ms[b*4+2]=mean[2];
    ms[b*4+3]=red[0]*2.0f;
  }
}

// ---------------- norm coords + voxel index ----------------
__global__ void k_assign(const float* __restrict__ coords, const float* __restrict__ ms,
                         float* __restrict__ nc, int* __restrict__ vi){
  int t = blockIdx.x*256+threadIdx.x;
  if(t>=BB*NP) return;
  int b=t/NP, n=t-b*NP;
  float scale=ms[b*4+3];
  int vox[3];
  #pragma unroll
  for(int d=0; d<3; d++){
    float c=coords[(b*3+d)*NP+n] - ms[b*4+d];
    float v=(c/scale + 0.5f)*32.0f;
    v=fminf(fmaxf(v,0.0f),31.0f);
    nc[(b*3+d)*NP+n]=v;
    vox[d]=(int)rintf(v);
  }
  vi[t]=vox[0]*1024+vox[1]*32+vox[2];
}

// --------- scatter: one wave per point, lane = channel ----------
__global__ void k_scatter(const float* __restrict__ feat, const int* __restrict__ vi,
                          float* __restrict__ gsum, float* __restrict__ cnt){
  int wid = (blockIdx.x*256+threadIdx.x)>>6;
  int lane = threadIdx.x&63;
  if(wid>=BB*NP) return;
  int b=wid>>12, n=wid&4095;
  int idx=vi[wid];
  float f = feat[((size_t)(b*CH+lane))*NP + n];
  atomicAdd(gsum + ((size_t)b*R3+idx)*CH + lane, f);
  if(lane==0) atomicAdd(&cnt[b*R3+idx], 1.0f);
}

// ---------------- sums -> means, f32 -> bf16 grid ----------------
__global__ void k_gridmean(const float* __restrict__ gsum, const float* __restrict__ cnt,
                           short* __restrict__ gbf){
  int t=blockIdx.x*256+threadIdx.x;
  if(t>=BB*R3*8) return;
  int v=t>>3, q=t&7;
  float inv=1.0f/fmaxf(cnt[v],1.0f);
  const float* sp=gsum + (size_t)v*CH + q*8;
  short8 o;
  #pragma unroll
  for(int j=0;j<8;j++) o[j]=f2bf(sp[j]*inv);
  ((short8*)gbf)[(size_t)v*8+q]=o;
}

// ------- both conv weights -> per-fragment contiguous bf16 (merged) -------
__global__ void k_wt3x2(const float* __restrict__ wa, const float* __restrict__ wb,
                        short* __restrict__ oa, short* __restrict__ ob){
  int t=blockIdx.x*256+threadIdx.x;
  if(t>=2*CH*CH*27) return;
  const float* w = (t<CH*CH*27)? wa : wb;
  short* o = (t<CH*CH*27)? oa : ob;
  int tt = (t<CH*CH*27)? t : t-CH*CH*27;
  int frag=tt>>9, l=(tt>>3)&63, j=tt&7;
  int tap=frag>>3, hh=(frag>>2)&1, nf=frag&3;
  int oc=nf*16+(l&15);
  int ci=hh*32+(l>>4)*8+j;
  o[tt]=f2bf(w[oc*1728 + ci*27 + tap]);
}

// ------------- MFMA implicit-GEMM 3x3x3 conv + bias + BN + leaky -------------
// tile 4z x 8y x 8x, 4 waves (wave = z-layer, M=64 rows), ci in 2 halves of 32.
// h1 loads prefetched to regs under h0 compute (T14).
#define CONV_COMPUTE(WB) do{ \
  short8 bw0[4], bw1[4], aA[4], aB[4]; \
  _Pragma("unroll") for(int nf=0;nf<4;nf++) bw0[nf]=WB[nf*64]; \
  _Pragma("unroll") for(int nf=0;nf<4;nf++) bw1[nf]=WB[512+nf*64]; \
  _Pragma("unroll") for(int mf=0;mf<4;mf++){ int cell=zl*100+(iyq+mf*2)*10+ix; aA[mf]=s8[g*601+cell]; } \
  for(int tt=0; tt<27; tt+=2){ \
    if(tt+1<27){ \
      int t1=tt+1, kz=t1/9, r=t1-kz*9, ky=r/3, kx=r-ky*3; \
      _Pragma("unroll") for(int mf=0;mf<4;mf++){ \
        int cell=(zl+kz)*100+(iyq+mf*2+ky)*10+ix+kx; aB[mf]=s8[g*601+cell]; } \
    } \
    _Pragma("unroll") for(int mf=0;mf<4;mf++) \
      _Pragma("unroll") for(int nf=0;nf<4;nf++) \
        acc[mf][nf]=__builtin_amdgcn_mfma_f32_16x16x32_bf16(aA[mf],bw0[nf],acc[mf][nf],0,0,0); \
    if(tt+2<27){ _Pragma("unroll") for(int nf=0;nf<4;nf++) bw0[nf]=WB[(tt+2)*512+nf*64]; } \
    if(tt+1<27){ \
      if(tt+2<27){ \
        int t2=tt+2, kz=t2/9, r=t2-kz*9, ky=r/3, kx=r-ky*3; \
        _Pragma("unroll") for(int mf=0;mf<4;mf++){ \
          int cell=(zl+kz)*100+(iyq+mf*2+ky)*10+ix+kx; aA[mf]=s8[g*601+cell]; } \
      } \
      _Pragma("unroll") for(int mf=0;mf<4;mf++) \
        _Pragma("unroll") for(int nf=0;nf<4;nf++) \
          acc[mf][nf]=__builtin_amdgcn_mfma_f32_16x16x32_bf16(aB[mf],bw1[nf],acc[mf][nf],0,0,0); \
      if(tt+3<27){ _Pragma("unroll") for(int nf=0;nf<4;nf++) bw1[nf]=WB[(tt+3)*512+nf*64]; } \
    } \
  } \
}while(0)

__global__ __launch_bounds__(256,3) void k_conv_mfma(
    const short* __restrict__ gin, short* __restrict__ gout,
    const short* __restrict__ wt3, const float* __restrict__ bias,
    const float* __restrict__ bg, const float* __restrict__ bb,
    const float* __restrict__ bm, const float* __restrict__ bv){
  __shared__ __align__(16) short in_s[4*601*8];   // 38464 B
  int tid=threadIdx.x;
  int blk=blockIdx.x;                 // 8b x 8zt x 4yt x 4xt = 1024
  int b=blk>>7, zt=(blk>>4)&7, yt=(blk>>2)&3, xt=blk&3;
  int z0=zt*4, y0=yt*8, x0=xt*8;
  const short* gbase = gin + (size_t)b*R3*CH;

  int lane=tid&63, zl=tid>>6;
  int r15=lane&15, g=lane>>4;
  int ix=r15&7, iyq=r15>>3;

  float4_ acc[4][4];
  #pragma unroll
  for(int mf=0;mf<4;mf++)
    #pragma unroll
    for(int nf=0;nf<4;nf++) acc[mf][nf]=(float4_){0.f,0.f,0.f,0.f};

  short8* s8=(short8*)in_s;

  // ---- stage ci-half 0 directly ----
  #pragma unroll
  for(int it=0;it<10;it++){
    int e=tid+it*256;
    if(e<2400){
      int ss=e>>2, cb=e&3;
      int z=ss/100, r2=ss-z*100, y=r2/10, x=r2-y*10;
      int gz=z0-1+z, gy=y0-1+y, gx=x0-1+x;
      short8 v={0,0,0,0,0,0,0,0};
      if(((unsigned)gz<32u)&&((unsigned)gy<32u)&&((unsigned)gx<32u))
        v=*(const short8*)(gbase + ((gz<<10)+(gy<<5)+gx)*CH + cb*8);
      s8[cb*601+ss]=v;
    }
  }
  __syncthreads();

  // ---- prefetch ci-half 1 into registers (hidden under h0 compute) ----
  short8 pf[10];
  #pragma unroll
  for(int it=0;it<10;it++){
    int e=tid+it*256;
    short8 v={0,0,0,0,0,0,0,0};
    if(e<2400){
      int ss=e>>2, cb=e&3;
      int z=ss/100, r2=ss-z*100, y=r2/10, x=r2-y*10;
      int gz=z0-1+z, gy=y0-1+y, gx=x0-1+x;
      if(((unsigned)gz<32u)&&((unsigned)gy<32u)&&((unsigned)gx<32u))
        v=*(const short8*)(gbase + ((gz<<10)+(gy<<5)+gx)*CH + 32 + cb*8);
    }
    pf[it]=v;
  }
  asm volatile("" ::: "memory");   // pin load issue before compute

  const short8* wb0 = ((const short8*)wt3) + lane;
  const short8* wb1 = ((const short8*)wt3) + 256 + lane;
  CONV_COMPUTE(wb0);

  __syncthreads();
  #pragma unroll
  for(int it=0;it<10;it++){
    int e=tid+it*256;
    if(e<2400){
      int ss=e>>2, cb=e&3;
      s8[cb*601+ss]=pf[it];
    }
  }
  __syncthreads();
  CONV_COMPUTE(wb1);

  // ---- epilogue: bias + BN + leaky -> LDS bf16 repack -> coalesced stores ----
  __syncthreads();
  short* ot=(short*)in_s;             // [256 rows][stride 72] = 36864 B
  #pragma unroll
  for(int nf=0;nf<4;nf++){
    int oc=nf*16+r15;
    float iv=bg[oc]/sqrtf(bv[oc]+BNEPS);
    float sh=bias[oc]*iv + bb[oc]-bm[oc]*iv;
    #pragma unroll
    for(int mf=0;mf<4;mf++){
      #pragma unroll
      for(int q=0;q<4;q++){
        int row=mf*16+g*4+q;
        float val=acc[mf][nf][q]*iv+sh;
        val = val>=0.f ? val : LEAK*val;
        ot[(zl*64+row)*72 + oc]=f2bf(val);
      }
    }
  }
  __syncthreads();
  short* go = gout + (size_t)b*R3*CH;
  #pragma unroll
  for(int it=0;it<8;it++){
    int e=tid+it*256;
    int vr=e>>3, j=e&7;
    int zz=vr>>6, rr=vr&63;
    short8 v=*(short8*)(ot + vr*72 + j*8);
    *(short8*)(go + ((size_t)((z0+zz)*1024 + (y0+(rr>>3))*32 + x0+(rr&7)))*CH + j*8)=v;
  }
}

// ------- point MLP + fused GN partial stats -------
__global__ __launch_bounds__(256,2) void k_ptgemm(
    const float* __restrict__ feat, const float* __restrict__ w,
    const float* __restrict__ bias, float* __restrict__ y,
    float* __restrict__ stp){
  __shared__ float ws_[64*64];
  __shared__ float ft[64][65];
  __shared__ float sg[8], qg[8];
  int tid=threadIdx.x;
  int blk=blockIdx.x;
  int b=blk>>6, n0=(blk&63)*64;
  for(int e=tid;e<4096;e+=256) ws_[e]=w[e];
  for(int e=tid;e<4096;e+=256){
    int c=e>>6, nl=e&63;
    ft[c][nl]=feat[(size_t)(b*CH+c)*NP + n0+nl];
  }
  if(tid<8){ sg[tid]=0.f; qg[tid]=0.f; }
  __syncthreads();
  int nl=tid&63, qq=tid>>6;
  float ps[2]={0.f,0.f}, pq[2]={0.f,0.f};
  #pragma unroll
  for(int j=0;j<16;j++){
    int o=qq*16+j;
    float a=bias[o];
    #pragma unroll
    for(int c=0;c<64;c++) a=fmaf(ws_[o*64+c], ft[c][nl], a);
    y[(size_t)(b*CH+o)*NP+n0+nl]=a;
    int gi=j>>3;
    ps[gi]+=a; pq[gi]+=a*a;
  }
  #pragma unroll
  for(int off=32;off>0;off>>=1){
    ps[0]+=__shfl_down(ps[0],off,64); pq[0]+=__shfl_down(pq[0],off,64);
    ps[1]+=__shfl_down(ps[1],off,64); pq[1]+=__shfl_down(pq[1],off,64);
  }
  if((tid&63)==0){
    atomicAdd(&sg[qq*2+0],ps[0]); atomicAdd(&qg[qq*2+0],pq[0]);
    atomicAdd(&sg[qq*2+1],ps[1]); atomicAdd(&qg[qq*2+1],pq[1]);
  }
  __syncthreads();
  if(tid<8){
    atomicAdd(&stp[(b*8+tid)*2+0], sg[tid]);
    atomicAdd(&stp[(b*8+tid)*2+1], qg[tid]);
  }
}

// ------- devoxelize + GN finalize + affine + swish + add; coalesced out -------
__global__ void k_fuse(const short* __restrict__ grid, const float* __restrict__ nc,
                       const float* __restrict__ py, const float* __restrict__ stp,
                       const float* __restrict__ gg, const float* __restrict__ gb,
                       float* __restrict__ out){
  __shared__ float ot[64][65];
  __shared__ float gmu[8], grs[8];
  int tid=threadIdx.x;
  int blk=blockIdx.x;
  int b=blk>>6, n0=(blk&63)*64;
  int nl=tid>>2, qq=tid&3;
  int n=n0+nl;

  if(tid<8){
    float s=stp[(b*8+tid)*2+0], q=stp[(b*8+tid)*2+1];
    float mu=s/(8.f*NP);
    float var=q/(8.f*NP)-mu*mu;
    gmu[tid]=mu;
    grs[tid]=1.0f/sqrtf(var+GNEPS);
  }
  __syncthreads();

  float d_[3]; int i0[3], i1[3];
  #pragma unroll
  for(int dd=0;dd<3;dd++){
    float c=nc[(b*3+dd)*NP+n];
    c=fminf(fmaxf(c,0.f),31.f);
    float f=floorf(c);
    d_[dd]=c-f;
    i0[dd]=(int)f;
    i1[dd]=min(i0[dd]+1,31);
  }
  int idx8[8]; float w8[8];
  #pragma unroll
  for(int k=0;k<8;k++){
    int xx=(k&4)?i1[0]:i0[0];
    int yy=(k&2)?i1[1]:i0[1];
    int zz=(k&1)?i1[2]:i0[2];
    float wx=(k&4)?d_[0]:(1.f-d_[0]);
    float wy=(k&2)?d_[1]:(1.f-d_[1]);
    float wz=(k&1)?d_[2]:(1.f-d_[2]);
    idx8[k]=xx*1024+yy*32+zz;
    w8[k]=wx*wy*wz;
  }
  const short* gbase = grid + (size_t)b*R3*CH;
  #pragma unroll
  for(int c8=0;c8<2;c8++){
    int c0=qq*16+c8*8;
    float dv[8]={0.f,0.f,0.f,0.f,0.f,0.f,0.f,0.f};
    #pragma unroll
    for(int k=0;k<8;k++){
      short8 gv=*(const short8*)(gbase + (size_t)idx8[k]*CH + c0);
      #pragma unroll
      for(int j=0;j<8;j++) dv[j]+=w8[k]*bf2f(gv[j]);
    }
    #pragma unroll
    for(int j=0;j<8;j++){
      int c=c0+j;
      float yn=(py[(size_t)(b*CH+c)*NP+n]-gmu[c>>3])*grs[c>>3]*gg[c]+gb[c];
      float sw=yn/(1.f+expf(-yn));
      ot[c][nl]=dv[j]+sw;
    }
  }
  __syncthreads();
  for(int i=tid;i<1024;i+=256){
    int c=i>>4, sg=i&15;
    float4_ v={ot[c][sg*4+0],ot[c][sg*4+1],ot[c][sg*4+2],ot[c][sg*4+3]};
    *(float4_*)(out + (size_t)(b*CH+c)*NP + n0 + sg*4) = v;
  }
}

// ---------------- merged passthrough copy (coords + temb) ----------------
__global__ void k_copyall(const float* __restrict__ coords, const float* __restrict__ temb,
                          float* __restrict__ out){
  int t=blockIdx.x*256+threadIdx.x;
  if(t<98304) out[2097152+t]=coords[t];
  else if(t<98816) out[2195456+(t-98304)]=temb[t-98304];
}

extern "C" void kernel_launch(void* const* d_in, const int* in_sizes, int n_in,
                              void* d_out, int out_size, void* d_ws, size_t ws_size,
                              hipStream_t stream){
  const float* features=(const float*)d_in[0];
  const float* coords  =(const float*)d_in[1];
  const float* temb    =(const float*)d_in[2];
  const float* c1w=(const float*)d_in[3];
  const float* c1b=(const float*)d_in[4];
  const float* b1g=(const float*)d_in[5];
  const float* b1b=(const float*)d_in[6];
  const float* b1m=(const float*)d_in[7];
  const float* b1v=(const float*)d_in[8];
  const float* c2w=(const float*)d_in[9];
  const float* c2b=(const float*)d_in[10];
  const float* b2g=(const float*)d_in[11];
  const float* b2b=(const float*)d_in[12];
  const float* b2m=(const float*)d_in[13];
  const float* b2v=(const float*)d_in[14];
  const float* pfw=(const float*)d_in[15];
  const float* pfb=(const float*)d_in[16];
  const float* gng=(const float*)d_in[17];
  const float* gnb=(const float*)d_in[18];

  float* F=(float*)d_ws;
  float* ms  = F + 0;                   // 32
  float* nc  = F + 32;                  // 98304
  int*   vi  = (int*)(F + 98336);       // 32768
  short* w1t = (short*)(F + 131104);    // 110592 sh = 55296 f
  short* w2t = (short*)(F + 186400);    // 55296 f
  float* py  = F + 241696;              // 2097152
  float* stp = F + 2338848;             // 128  (memset start)
  float* cnt = F + 2338976;             // 262144
  float* gA  = F + 2601120;             // 16777216
  short* gBF1= (short*)(F + 19378336);  // 16777216 sh = 8388608 f
  short* gBF2= (short*)(F + 27766944);  // 8388608 f
  float* out=(float*)d_out;

  hipMemsetAsync(stp, 0, (size_t)(128+262144+16777216)*4, stream);

  k_voxstats<<<8,256,0,stream>>>(coords, ms);
  k_assign  <<<128,256,0,stream>>>(coords, ms, nc, vi);
  k_scatter <<<8192,256,0,stream>>>(features, vi, gA, cnt);
  k_gridmean<<<8192,256,0,stream>>>(gA, cnt, gBF1);
  k_wt3x2   <<<864,256,0,stream>>>(c1w, c2w, w1t, w2t);
  k_conv_mfma<<<1024,256,0,stream>>>(gBF1, gBF2, w1t, c1b, b1g, b1b, b1m, b1v);
  k_conv_mfma<<<1024,256,0,stream>>>(gBF2, gBF1, w2t, c2b, b2g, b2b, b2m, b2v);
  k_ptgemm  <<<512,256,0,stream>>>(features, pfw, pfb, py, stp);
  k_fuse    <<<512,256,0,stream>>>(gBF1, nc, py, stp, gng, gnb, out);
  k_copyall <<<386,256,0,stream>>>(coords, temb, out);
}

// Round 11
// 248.090 us; speedup vs baseline: 1.4147x; 1.0750x over previous
//
#include <hip/hip_runtime.h>
#include <hip/hip_bf16.h>
#include <math.h>

#define BB 8
#define CH 64
#define NP 4096
#define RG 32
#define R3 32768
#define LEAK 0.2f
#define BNEPS 1e-5f
#define GNEPS 1e-5f
#define SSTR 602   // LDS cb-region stride (units of 16B); 602%8==2 -> conflict-free stage stores

typedef short short8 __attribute__((ext_vector_type(8)));
typedef float float4_ __attribute__((ext_vector_type(4)));

__device__ __forceinline__ short f2bf(float f){
  unsigned u = __float_as_uint(f);
  u += 0x7FFF + ((u>>16)&1);          // RNE
  return (short)(u>>16);
}
__device__ __forceinline__ float bf2f(short s){
  unsigned u = ((unsigned)(unsigned short)s)<<16;
  return __uint_as_float(u);
}

// ---------------- voxelize stats ----------------
__global__ void k_voxstats(const float* __restrict__ coords, float* __restrict__ ms){
  int b = blockIdx.x;
  __shared__ float red[256];
  float mean[3];
  for(int d=0; d<3; d++){
    float s=0.f;
    for(int i=threadIdx.x; i<NP; i+=256) s += coords[(b*3+d)*NP+i];
    red[threadIdx.x]=s; __syncthreads();
    for(int o=128;o>0;o>>=1){ if(threadIdx.x<o) red[threadIdx.x]+=red[threadIdx.x+o]; __syncthreads(); }
    mean[d]=red[0]/(float)NP; __syncthreads();
  }
  float mx=0.f;
  for(int i=threadIdx.x; i<NP; i+=256){
    float x=coords[(b*3+0)*NP+i]-mean[0];
    float y=coords[(b*3+1)*NP+i]-mean[1];
    float z=coords[(b*3+2)*NP+i]-mean[2];
    mx=fmaxf(mx, sqrtf(x*x+y*y+z*z));
  }
  red[threadIdx.x]=mx; __syncthreads();
  for(int o=128;o>0;o>>=1){ if(threadIdx.x<o) red[threadIdx.x]=fmaxf(red[threadIdx.x],red[threadIdx.x+o]); __syncthreads(); }
  if(threadIdx.x==0){
    ms[b*4+0]=mean[0]; ms[b*4+1]=mean[1]; ms[b*4+2]=mean[2];
    ms[b*4+3]=red[0]*2.0f;
  }
}

// ---------------- norm coords + voxel index ----------------
__global__ void k_assign(const float* __restrict__ coords, const float* __restrict__ ms,
                         float* __restrict__ nc, int* __restrict__ vi){
  int t = blockIdx.x*256+threadIdx.x;
  if(t>=BB*NP) return;
  int b=t/NP, n=t-b*NP;
  float scale=ms[b*4+3];
  int vox[3];
  #pragma unroll
  for(int d=0; d<3; d++){
    float c=coords[(b*3+d)*NP+n] - ms[b*4+d];
    float v=(c/scale + 0.5f)*32.0f;
    v=fminf(fmaxf(v,0.0f),31.0f);
    nc[(b*3+d)*NP+n]=v;
    vox[d]=(int)rintf(v);
  }
  vi[t]=vox[0]*1024+vox[1]*32+vox[2];
}

// --------- scatter: one wave per point, lane = channel ----------
__global__ void k_scatter(const float* __restrict__ feat, const int* __restrict__ vi,
                          float* __restrict__ gsum, float* __restrict__ cnt){
  int wid = (blockIdx.x*256+threadIdx.x)>>6;
  int lane = threadIdx.x&63;
  if(wid>=BB*NP) return;
  int b=wid>>12, n=wid&4095;
  int idx=vi[wid];
  float f = feat[((size_t)(b*CH+lane))*NP + n];
  atomicAdd(gsum + ((size_t)b*R3+idx)*CH + lane, f);
  if(lane==0) atomicAdd(&cnt[b*R3+idx], 1.0f);
}

// ---------------- sums -> means, f32 -> bf16 grid ----------------
__global__ void k_gridmean(const float* __restrict__ gsum, const float* __restrict__ cnt,
                           short* __restrict__ gbf){
  int t=blockIdx.x*256+threadIdx.x;
  if(t>=BB*R3*8) return;
  int v=t>>3, q=t&7;
  float inv=1.0f/fmaxf(cnt[v],1.0f);
  const float* sp=gsum + (size_t)v*CH + q*8;
  short8 o;
  #pragma unroll
  for(int j=0;j<8;j++) o[j]=f2bf(sp[j]*inv);
  ((short8*)gbf)[(size_t)v*8+q]=o;
}

// ------- both conv weights -> per-fragment contiguous bf16 (merged) -------
__global__ void k_wt3x2(const float* __restrict__ wa, const float* __restrict__ wb,
                        short* __restrict__ oa, short* __restrict__ ob){
  int t=blockIdx.x*256+threadIdx.x;
  if(t>=2*CH*CH*27) return;
  const float* w = (t<CH*CH*27)? wa : wb;
  short* o = (t<CH*CH*27)? oa : ob;
  int tt = (t<CH*CH*27)? t : t-CH*CH*27;
  int frag=tt>>9, l=(tt>>3)&63, j=tt&7;
  int tap=frag>>3, hh=(frag>>2)&1, nf=frag&3;
  int oc=nf*16+(l&15);
  int ci=hh*32+(l>>4)*8+j;
  o[tt]=f2bf(w[oc*1728 + ci*27 + tap]);
}

// ------------- MFMA implicit-GEMM 3x3x3 conv + bias + BN + leaky -------------
// tile 4z x 8y x 8x, 4 waves (wave = z-layer, M=64 rows), ci in 2 halves of 32.
// grid 1024 = 4 blocks/CU, launch_bounds(256,4) -> ALL blocks co-resident.
#define CONV_COMPUTE(WB) do{ \
  short8 bw0[4], bw1[4], aA[4], aB[4]; \
  _Pragma("unroll") for(int nf=0;nf<4;nf++) bw0[nf]=WB[nf*64]; \
  _Pragma("unroll") for(int nf=0;nf<4;nf++) bw1[nf]=WB[512+nf*64]; \
  _Pragma("unroll") for(int mf=0;mf<4;mf++){ int cell=zl*100+(iyq+mf*2)*10+ix; aA[mf]=s8[g*SSTR+cell]; } \
  for(int tt=0; tt<27; tt+=2){ \
    if(tt+1<27){ \
      int t1=tt+1, kz=t1/9, r=t1-kz*9, ky=r/3, kx=r-ky*3; \
      _Pragma("unroll") for(int mf=0;mf<4;mf++){ \
        int cell=(zl+kz)*100+(iyq+mf*2+ky)*10+ix+kx; aB[mf]=s8[g*SSTR+cell]; } \
    } \
    _Pragma("unroll") for(int mf=0;mf<4;mf++) \
      _Pragma("unroll") for(int nf=0;nf<4;nf++) \
        acc[mf][nf]=__builtin_amdgcn_mfma_f32_16x16x32_bf16(aA[mf],bw0[nf],acc[mf][nf],0,0,0); \
    if(tt+2<27){ _Pragma("unroll") for(int nf=0;nf<4;nf++) bw0[nf]=WB[(tt+2)*512+nf*64]; } \
    if(tt+1<27){ \
      if(tt+2<27){ \
        int t2=tt+2, kz=t2/9, r=t2-kz*9, ky=r/3, kx=r-ky*3; \
        _Pragma("unroll") for(int mf=0;mf<4;mf++){ \
          int cell=(zl+kz)*100+(iyq+mf*2+ky)*10+ix+kx; aA[mf]=s8[g*SSTR+cell]; } \
      } \
      _Pragma("unroll") for(int mf=0;mf<4;mf++) \
        _Pragma("unroll") for(int nf=0;nf<4;nf++) \
          acc[mf][nf]=__builtin_amdgcn_mfma_f32_16x16x32_bf16(aB[mf],bw1[nf],acc[mf][nf],0,0,0); \
      if(tt+3<27){ _Pragma("unroll") for(int nf=0;nf<4;nf++) bw1[nf]=WB[(tt+3)*512+nf*64]; } \
    } \
  } \
}while(0)

__global__ __launch_bounds__(256,4) void k_conv_mfma(
    const short* __restrict__ gin, short* __restrict__ gout,
    const short* __restrict__ wt3, const float* __restrict__ bias,
    const float* __restrict__ bg, const float* __restrict__ bb,
    const float* __restrict__ bm, const float* __restrict__ bv){
  __shared__ __align__(16) short in_s[4*SSTR*8];   // 38528 B; x4 blocks = 154 KB/CU
  int tid=threadIdx.x;
  int blk=blockIdx.x;                 // 8b x 8zt x 4yt x 4xt = 1024
  int b=blk>>7, zt=(blk>>4)&7, yt=(blk>>2)&3, xt=blk&3;
  int z0=zt*4, y0=yt*8, x0=xt*8;
  const short* gbase = gin + (size_t)b*R3*CH;

  int lane=tid&63, zl=tid>>6;
  int r15=lane&15, g=lane>>4;
  int ix=r15&7, iyq=r15>>3;

  float4_ acc[4][4];
  #pragma unroll
  for(int mf=0;mf<4;mf++)
    #pragma unroll
    for(int nf=0;nf<4;nf++) acc[mf][nf]=(float4_){0.f,0.f,0.f,0.f};

  short8* s8=(short8*)in_s;

  for(int hh=0; hh<2; hh++){
    __syncthreads();
    // stage 6z x 10y x 10x halo, ci half hh (32 ch = 4 cb of 8), bounds-checked
    for(int e=tid; e<2400; e+=256){
      int ss=e>>2, cb=e&3;
      int z=ss/100, r2=ss-z*100, y=r2/10, x=r2-y*10;
      int gz=z0-1+z, gy=y0-1+y, gx=x0-1+x;
      short8 v={0,0,0,0,0,0,0,0};
      if(((unsigned)gz<32u)&&((unsigned)gy<32u)&&((unsigned)gx<32u))
        v=*(const short8*)(gbase + ((gz<<10)+(gy<<5)+gx)*CH + hh*32 + cb*8);
      s8[cb*SSTR+ss]=v;
    }
    __syncthreads();

    const short8* wb = ((const short8*)wt3) + hh*256 + lane;
    CONV_COMPUTE(wb);
  }

  // ---- epilogue: bias + BN + leaky -> LDS bf16 repack -> coalesced stores ----
  __syncthreads();
  short* ot=(short*)in_s;             // [256 rows][stride 72] = 36864 B
  #pragma unroll
  for(int nf=0;nf<4;nf++){
    int oc=nf*16+r15;
    float iv=bg[oc]/sqrtf(bv[oc]+BNEPS);
    float sh=bias[oc]*iv + bb[oc]-bm[oc]*iv;
    #pragma unroll
    for(int mf=0;mf<4;mf++){
      #pragma unroll
      for(int q=0;q<4;q++){
        int row=mf*16+g*4+q;
        float val=acc[mf][nf][q]*iv+sh;
        val = val>=0.f ? val : LEAK*val;
        ot[(zl*64+row)*72 + oc]=f2bf(val);
      }
    }
  }
  __syncthreads();
  short* go = gout + (size_t)b*R3*CH;
  #pragma unroll
  for(int it=0;it<8;it++){
    int e=tid+it*256;
    int vr=e>>3, j=e&7;
    int zz=vr>>6, rr=vr&63;
    short8 v=*(short8*)(ot + vr*72 + j*8);
    *(short8*)(go + ((size_t)((z0+zz)*1024 + (y0+(rr>>3))*32 + x0+(rr&7)))*CH + j*8)=v;
  }
}

// ------- point MLP + fused GN partial stats -------
__global__ __launch_bounds__(256,2) void k_ptgemm(
    const float* __restrict__ feat, const float* __restrict__ w,
    const float* __restrict__ bias, float* __restrict__ y,
    float* __restrict__ stp){
  __shared__ float ws_[64*64];
  __shared__ float ft[64][65];
  __shared__ float sg[8], qg[8];
  int tid=threadIdx.x;
  int blk=blockIdx.x;
  int b=blk>>6, n0=(blk&63)*64;
  for(int e=tid;e<4096;e+=256) ws_[e]=w[e];
  for(int e=tid;e<4096;e+=256){
    int c=e>>6, nl=e&63;
    ft[c][nl]=feat[(size_t)(b*CH+c)*NP + n0+nl];
  }
  if(tid<8){ sg[tid]=0.f; qg[tid]=0.f; }
  __syncthreads();
  int nl=tid&63, qq=tid>>6;
  float ps[2]={0.f,0.f}, pq[2]={0.f,0.f};
  #pragma unroll
  for(int j=0;j<16;j++){
    int o=qq*16+j;
    float a=bias[o];
    #pragma unroll
    for(int c=0;c<64;c++) a=fmaf(ws_[o*64+c], ft[c][nl], a);
    y[(size_t)(b*CH+o)*NP+n0+nl]=a;
    int gi=j>>3;
    ps[gi]+=a; pq[gi]+=a*a;
  }
  #pragma unroll
  for(int off=32;off>0;off>>=1){
    ps[0]+=__shfl_down(ps[0],off,64); pq[0]+=__shfl_down(pq[0],off,64);
    ps[1]+=__shfl_down(ps[1],off,64); pq[1]+=__shfl_down(pq[1],off,64);
  }
  if((tid&63)==0){
    atomicAdd(&sg[qq*2+0],ps[0]); atomicAdd(&qg[qq*2+0],pq[0]);
    atomicAdd(&sg[qq*2+1],ps[1]); atomicAdd(&qg[qq*2+1],pq[1]);
  }
  __syncthreads();
  if(tid<8){
    atomicAdd(&stp[(b*8+tid)*2+0], sg[tid]);
    atomicAdd(&stp[(b*8+tid)*2+1], qg[tid]);
  }
}

// ------- devoxelize + GN finalize + affine + swish + add; coalesced out -------
__global__ void k_fuse(const short* __restrict__ grid, const float* __restrict__ nc,
                       const float* __restrict__ py, const float* __restrict__ stp,
                       const float* __restrict__ gg, const float* __restrict__ gb,
                       float* __restrict__ out){
  __shared__ float ot[64][65];
  __shared__ float gmu[8], grs[8];
  int tid=threadIdx.x;
  int blk=blockIdx.x;
  int b=blk>>6, n0=(blk&63)*64;
  int nl=tid>>2, qq=tid&3;
  int n=n0+nl;

  if(tid<8){
    float s=stp[(b*8+tid)*2+0], q=stp[(b*8+tid)*2+1];
    float mu=s/(8.f*NP);
    float var=q/(8.f*NP)-mu*mu;
    gmu[tid]=mu;
    grs[tid]=1.0f/sqrtf(var+GNEPS);
  }
  __syncthreads();

  float d_[3]; int i0[3], i1[3];
  #pragma unroll
  for(int dd=0;dd<3;dd++){
    float c=nc[(b*3+dd)*NP+n];
    c=fminf(fmaxf(c,0.f),31.f);
    float f=floorf(c);
    d_[dd]=c-f;
    i0[dd]=(int)f;
    i1[dd]=min(i0[dd]+1,31);
  }
  int idx8[8]; float w8[8];
  #pragma unroll
  for(int k=0;k<8;k++){
    int xx=(k&4)?i1[0]:i0[0];
    int yy=(k&2)?i1[1]:i0[1];
    int zz=(k&1)?i1[2]:i0[2];
    float wx=(k&4)?d_[0]:(1.f-d_[0]);
    float wy=(k&2)?d_[1]:(1.f-d_[1]);
    float wz=(k&1)?d_[2]:(1.f-d_[2]);
    idx8[k]=xx*1024+yy*32+zz;
    w8[k]=wx*wy*wz;
  }
  const short* gbase = grid + (size_t)b*R3*CH;
  #pragma unroll
  for(int c8=0;c8<2;c8++){
    int c0=qq*16+c8*8;
    float dv[8]={0.f,0.f,0.f,0.f,0.f,0.f,0.f,0.f};
    #pragma unroll
    for(int k=0;k<8;k++){
      short8 gv=*(const short8*)(gbase + (size_t)idx8[k]*CH + c0);
      #pragma unroll
      for(int j=0;j<8;j++) dv[j]+=w8[k]*bf2f(gv[j]);
    }
    #pragma unroll
    for(int j=0;j<8;j++){
      int c=c0+j;
      float yn=(py[(size_t)(b*CH+c)*NP+n]-gmu[c>>3])*grs[c>>3]*gg[c]+gb[c];
      float sw=yn/(1.f+expf(-yn));
      ot[c][nl]=dv[j]+sw;
    }
  }
  __syncthreads();
  for(int i=tid;i<1024;i+=256){
    int c=i>>4, sg=i&15;
    float4_ v={ot[c][sg*4+0],ot[c][sg*4+1],ot[c][sg*4+2],ot[c][sg*4+3]};
    *(float4_*)(out + (size_t)(b*CH+c)*NP + n0 + sg*4) = v;
  }
}

// ---------------- merged passthrough copy (coords + temb) ----------------
__global__ void k_copyall(const float* __restrict__ coords, const float* __restrict__ temb,
                          float* __restrict__ out){
  int t=blockIdx.x*256+threadIdx.x;
  if(t<98304) out[2097152+t]=coords[t];
  else if(t<98816) out[2195456+(t-98304)]=temb[t-98304];
}

extern "C" void kernel_launch(void* const* d_in, const int* in_sizes, int n_in,
                              void* d_out, int out_size, void* d_ws, size_t ws_size,
                              hipStream_t stream){
  const float* features=(const float*)d_in[0];
  const float* coords  =(const float*)d_in[1];
  const float* temb    =(const float*)d_in[2];
  const float* c1w=(const float*)d_in[3];
  const float* c1b=(const float*)d_in[4];
  const float* b1g=(const float*)d_in[5];
  const float* b1b=(const float*)d_in[6];
  const float* b1m=(const float*)d_in[7];
  const float* b1v=(const float*)d_in[8];
  const float* c2w=(const float*)d_in[9];
  const float* c2b=(const float*)d_in[10];
  const float* b2g=(const float*)d_in[11];
  const float* b2b=(const float*)d_in[12];
  const float* b2m=(const float*)d_in[13];
  const float* b2v=(const float*)d_in[14];
  const float* pfw=(const float*)d_in[15];
  const float* pfb=(const float*)d_in[16];
  const float* gng=(const float*)d_in[17];
  const float* gnb=(const float*)d_in[18];

  float* F=(float*)d_ws;
  float* ms  = F + 0;                   // 32
  float* nc  = F + 32;                  // 98304
  int*   vi  = (int*)(F + 98336);       // 32768
  short* w1t = (short*)(F + 131104);    // 110592 sh = 55296 f
  short* w2t = (short*)(F + 186400);    // 55296 f
  float* py  = F + 241696;              // 2097152
  float* stp = F + 2338848;             // 128  (memset start)
  float* cnt = F + 2338976;             // 262144
  float* gA  = F + 2601120;             // 16777216
  short* gBF1= (short*)(F + 19378336);  // 16777216 sh = 8388608 f
  short* gBF2= (short*)(F + 27766944);  // 8388608 f
  float* out=(float*)d_out;

  hipMemsetAsync(stp, 0, (size_t)(128+262144+16777216)*4, stream);

  k_voxstats<<<8,256,0,stream>>>(coords, ms);
  k_assign  <<<128,256,0,stream>>>(coords, ms, nc, vi);
  k_scatter <<<8192,256,0,stream>>>(features, vi, gA, cnt);
  k_gridmean<<<8192,256,0,stream>>>(gA, cnt, gBF1);
  k_wt3x2   <<<864,256,0,stream>>>(c1w, c2w, w1t, w2t);
  k_conv_mfma<<<1024,256,0,stream>>>(gBF1, gBF2, w1t, c1b, b1g, b1b, b1m, b1v);
  k_conv_mfma<<<1024,256,0,stream>>>(gBF2, gBF1, w2t, c2b, b2g, b2b, b2m, b2v);
  k_ptgemm  <<<512,256,0,stream>>>(features, pfw, pfb, py, stp);
  k_fuse    <<<512,256,0,stream>>>(gBF1, nc, py, stp, gng, gnb, out);
  k_copyall <<<386,256,0,stream>>>(coords, temb, out);
}

// Round 12
// 236.860 us; speedup vs baseline: 1.4817x; 1.0474x over previous
//
#include <hip/hip_runtime.h>
#include <hip/hip_bf16.h>
#include <math.h>

#define BB 8
#define CH 64
#define NP 4096
#define RG 32
#define R3 32768
#define LEAK 0.2f
#define BNEPS 1e-5f
#define GNEPS 1e-5f
#define SSTR 602   // LDS cb-region stride (units of 16B); 602%8==2 -> conflict-free stage stores

typedef short short8 __attribute__((ext_vector_type(8)));
typedef float float4_ __attribute__((ext_vector_type(4)));

__device__ __forceinline__ short f2bf(float f){
  unsigned u = __float_as_uint(f);
  u += 0x7FFF + ((u>>16)&1);          // RNE
  return (short)(u>>16);
}
__device__ __forceinline__ float bf2f(short s){
  unsigned u = ((unsigned)(unsigned short)s)<<16;
  return __uint_as_float(u);
}

// ---------------- voxelize stats ----------------
__global__ void k_voxstats(const float* __restrict__ coords, float* __restrict__ ms){
  int b = blockIdx.x;
  __shared__ float red[256];
  float mean[3];
  for(int d=0; d<3; d++){
    float s=0.f;
    for(int i=threadIdx.x; i<NP; i+=256) s += coords[(b*3+d)*NP+i];
    red[threadIdx.x]=s; __syncthreads();
    for(int o=128;o>0;o>>=1){ if(threadIdx.x<o) red[threadIdx.x]+=red[threadIdx.x+o]; __syncthreads(); }
    mean[d]=red[0]/(float)NP; __syncthreads();
  }
  float mx=0.f;
  for(int i=threadIdx.x; i<NP; i+=256){
    float x=coords[(b*3+0)*NP+i]-mean[0];
    float y=coords[(b*3+1)*NP+i]-mean[1];
    float z=coords[(b*3+2)*NP+i]-mean[2];
    mx=fmaxf(mx, sqrtf(x*x+y*y+z*z));
  }
  red[threadIdx.x]=mx; __syncthreads();
  for(int o=128;o>0;o>>=1){ if(threadIdx.x<o) red[threadIdx.x]=fmaxf(red[threadIdx.x],red[threadIdx.x+o]); __syncthreads(); }
  if(threadIdx.x==0){
    ms[b*4+0]=mean[0]; ms[b*4+1]=mean[1]; ms[b*4+2]=mean[2];
    ms[b*4+3]=red[0]*2.0f;
  }
}

// ---------------- norm coords + voxel index ----------------
__global__ void k_assign(const float* __restrict__ coords, const float* __restrict__ ms,
                         float* __restrict__ nc, int* __restrict__ vi){
  int t = blockIdx.x*256+threadIdx.x;
  if(t>=BB*NP) return;
  int b=t/NP, n=t-b*NP;
  float scale=ms[b*4+3];
  int vox[3];
  #pragma unroll
  for(int d=0; d<3; d++){
    float c=coords[(b*3+d)*NP+n] - ms[b*4+d];
    float v=(c/scale + 0.5f)*32.0f;
    v=fminf(fmaxf(v,0.0f),31.0f);
    nc[(b*3+d)*NP+n]=v;
    vox[d]=(int)rintf(v);
  }
  vi[t]=vox[0]*1024+vox[1]*32+vox[2];
}

// --------- scatter: one wave per point, lane = channel ----------
__global__ void k_scatter(const float* __restrict__ feat, const int* __restrict__ vi,
                          float* __restrict__ gsum, float* __restrict__ cnt){
  int wid = (blockIdx.x*256+threadIdx.x)>>6;
  int lane = threadIdx.x&63;
  if(wid>=BB*NP) return;
  int b=wid>>12, n=wid&4095;
  int idx=vi[wid];
  float f = feat[((size_t)(b*CH+lane))*NP + n];
  atomicAdd(gsum + ((size_t)b*R3+idx)*CH + lane, f);
  if(lane==0) atomicAdd(&cnt[b*R3+idx], 1.0f);
}

// ---------------- sums -> means, f32 -> bf16 grid ----------------
__global__ void k_gridmean(const float* __restrict__ gsum, const float* __restrict__ cnt,
                           short* __restrict__ gbf){
  int t=blockIdx.x*256+threadIdx.x;
  if(t>=BB*R3*8) return;
  int v=t>>3, q=t&7;
  float inv=1.0f/fmaxf(cnt[v],1.0f);
  const float* sp=gsum + (size_t)v*CH + q*8;
  short8 o;
  #pragma unroll
  for(int j=0;j<8;j++) o[j]=f2bf(sp[j]*inv);
  ((short8*)gbf)[(size_t)v*8+q]=o;
}

// ------- both conv weights -> per-fragment contiguous bf16 (merged) -------
__global__ void k_wt3x2(const float* __restrict__ wa, const float* __restrict__ wb,
                        short* __restrict__ oa, short* __restrict__ ob){
  int t=blockIdx.x*256+threadIdx.x;
  if(t>=2*CH*CH*27) return;
  const float* w = (t<CH*CH*27)? wa : wb;
  short* o = (t<CH*CH*27)? oa : ob;
  int tt = (t<CH*CH*27)? t : t-CH*CH*27;
  int frag=tt>>9, l=(tt>>3)&63, j=tt&7;
  int tap=frag>>3, hh=(frag>>2)&1, nf=frag&3;
  int oc=nf*16+(l&15);
  int ci=hh*32+(l>>4)*8+j;
  o[tt]=f2bf(w[oc*1728 + ci*27 + tap]);
}

// ------------- MFMA implicit-GEMM 3x3x3 conv + bias + BN + leaky -------------
// tile 4z x 8y x 8x, 4 waves (wave = z-layer, M=64 rows), ci in 2 halves of 32.
// grid 1024 = 4 blocks/CU, launch_bounds(256,4) -> ALL blocks co-resident.
// XCD-chunked swizzle: XCD k owns batch k -> halo reuse is XCD-local L2 hits.
#define CONV_COMPUTE(WB) do{ \
  short8 bw0[4], bw1[4], aA[4], aB[4]; \
  _Pragma("unroll") for(int nf=0;nf<4;nf++) bw0[nf]=WB[nf*64]; \
  _Pragma("unroll") for(int nf=0;nf<4;nf++) bw1[nf]=WB[512+nf*64]; \
  _Pragma("unroll") for(int mf=0;mf<4;mf++){ int cell=zl*100+(iyq+mf*2)*10+ix; aA[mf]=s8[g*SSTR+cell]; } \
  for(int tt=0; tt<27; tt+=2){ \
    if(tt+1<27){ \
      int t1=tt+1, kz=t1/9, r=t1-kz*9, ky=r/3, kx=r-ky*3; \
      _Pragma("unroll") for(int mf=0;mf<4;mf++){ \
        int cell=(zl+kz)*100+(iyq+mf*2+ky)*10+ix+kx; aB[mf]=s8[g*SSTR+cell]; } \
    } \
    _Pragma("unroll") for(int mf=0;mf<4;mf++) \
      _Pragma("unroll") for(int nf=0;nf<4;nf++) \
        acc[mf][nf]=__builtin_amdgcn_mfma_f32_16x16x32_bf16(aA[mf],bw0[nf],acc[mf][nf],0,0,0); \
    if(tt+2<27){ _Pragma("unroll") for(int nf=0;nf<4;nf++) bw0[nf]=WB[(tt+2)*512+nf*64]; } \
    if(tt+1<27){ \
      if(tt+2<27){ \
        int t2=tt+2, kz=t2/9, r=t2-kz*9, ky=r/3, kx=r-ky*3; \
        _Pragma("unroll") for(int mf=0;mf<4;mf++){ \
          int cell=(zl+kz)*100+(iyq+mf*2+ky)*10+ix+kx; aA[mf]=s8[g*SSTR+cell]; } \
      } \
      _Pragma("unroll") for(int mf=0;mf<4;mf++) \
        _Pragma("unroll") for(int nf=0;nf<4;nf++) \
          acc[mf][nf]=__builtin_amdgcn_mfma_f32_16x16x32_bf16(aB[mf],bw1[nf],acc[mf][nf],0,0,0); \
      if(tt+3<27){ _Pragma("unroll") for(int nf=0;nf<4;nf++) bw1[nf]=WB[(tt+3)*512+nf*64]; } \
    } \
  } \
}while(0)

__global__ __launch_bounds__(256,4) void k_conv_mfma(
    const short* __restrict__ gin, short* __restrict__ gout,
    const short* __restrict__ wt3, const float* __restrict__ bias,
    const float* __restrict__ bg, const float* __restrict__ bb,
    const float* __restrict__ bm, const float* __restrict__ bv){
  __shared__ __align__(16) short in_s[4*SSTR*8];   // 38528 B; x4 blocks = 154 KB/CU
  int tid=threadIdx.x;
  int bid=blockIdx.x;
  int blk=(bid&7)*128 + (bid>>3);     // XCD-chunked: XCD (bid%8) gets batch (bid%8)
  int b=blk>>7, zt=(blk>>4)&7, yt=(blk>>2)&3, xt=blk&3;
  int z0=zt*4, y0=yt*8, x0=xt*8;
  const short* gbase = gin + (size_t)b*R3*CH;

  int lane=tid&63, zl=tid>>6;
  int r15=lane&15, g=lane>>4;
  int ix=r15&7, iyq=r15>>3;

  float4_ acc[4][4];
  #pragma unroll
  for(int mf=0;mf<4;mf++)
    #pragma unroll
    for(int nf=0;nf<4;nf++) acc[mf][nf]=(float4_){0.f,0.f,0.f,0.f};

  short8* s8=(short8*)in_s;

  for(int hh=0; hh<2; hh++){
    __syncthreads();
    // stage 6z x 10y x 10x halo, ci half hh (32 ch = 4 cb of 8), bounds-checked
    for(int e=tid; e<2400; e+=256){
      int ss=e>>2, cb=e&3;
      int z=ss/100, r2=ss-z*100, y=r2/10, x=r2-y*10;
      int gz=z0-1+z, gy=y0-1+y, gx=x0-1+x;
      short8 v={0,0,0,0,0,0,0,0};
      if(((unsigned)gz<32u)&&((unsigned)gy<32u)&&((unsigned)gx<32u))
        v=*(const short8*)(gbase + ((gz<<10)+(gy<<5)+gx)*CH + hh*32 + cb*8);
      s8[cb*SSTR+ss]=v;
    }
    __syncthreads();

    const short8* wb = ((const short8*)wt3) + hh*256 + lane;
    CONV_COMPUTE(wb);
  }

  // ---- epilogue: bias + BN + leaky -> LDS bf16 repack -> coalesced stores ----
  __syncthreads();
  short* ot=(short*)in_s;             // [256 rows][stride 72] = 36864 B
  #pragma unroll
  for(int nf=0;nf<4;nf++){
    int oc=nf*16+r15;
    float iv=bg[oc]/sqrtf(bv[oc]+BNEPS);
    float sh=bias[oc]*iv + bb[oc]-bm[oc]*iv;
    #pragma unroll
    for(int mf=0;mf<4;mf++){
      #pragma unroll
      for(int q=0;q<4;q++){
        int row=mf*16+g*4+q;
        float val=acc[mf][nf][q]*iv+sh;
        val = val>=0.f ? val : LEAK*val;
        ot[(zl*64+row)*72 + oc]=f2bf(val);
      }
    }
  }
  __syncthreads();
  short* go = gout + (size_t)b*R3*CH;
  #pragma unroll
  for(int it=0;it<8;it++){
    int e=tid+it*256;
    int vr=e>>3, j=e&7;
    int zz=vr>>6, rr=vr&63;
    short8 v=*(short8*)(ot + vr*72 + j*8);
    *(short8*)(go + ((size_t)((z0+zz)*1024 + (y0+(rr>>3))*32 + x0+(rr&7)))*CH + j*8)=v;
  }
}

// ------- point MLP + fused GN partial stats -------
__global__ __launch_bounds__(256,2) void k_ptgemm(
    const float* __restrict__ feat, const float* __restrict__ w,
    const float* __restrict__ bias, float* __restrict__ y,
    float* __restrict__ stp){
  __shared__ float ws_[64*64];
  __shared__ float ft[64][65];
  __shared__ float sg[8], qg[8];
  int tid=threadIdx.x;
  int blk=blockIdx.x;
  int b=blk>>6, n0=(blk&63)*64;
  for(int e=tid;e<4096;e+=256) ws_[e]=w[e];
  for(int e=tid;e<4096;e+=256){
    int c=e>>6, nl=e&63;
    ft[c][nl]=feat[(size_t)(b*CH+c)*NP + n0+nl];
  }
  if(tid<8){ sg[tid]=0.f; qg[tid]=0.f; }
  __syncthreads();
  int nl=tid&63, qq=tid>>6;
  float ps[2]={0.f,0.f}, pq[2]={0.f,0.f};
  #pragma unroll
  for(int j=0;j<16;j++){
    int o=qq*16+j;
    float a=bias[o];
    #pragma unroll
    for(int c=0;c<64;c++) a=fmaf(ws_[o*64+c], ft[c][nl], a);
    y[(size_t)(b*CH+o)*NP+n0+nl]=a;
    int gi=j>>3;
    ps[gi]+=a; pq[gi]+=a*a;
  }
  #pragma unroll
  for(int off=32;off>0;off>>=1){
    ps[0]+=__shfl_down(ps[0],off,64); pq[0]+=__shfl_down(pq[0],off,64);
    ps[1]+=__shfl_down(ps[1],off,64); pq[1]+=__shfl_down(pq[1],off,64);
  }
  if((tid&63)==0){
    atomicAdd(&sg[qq*2+0],ps[0]); atomicAdd(&qg[qq*2+0],pq[0]);
    atomicAdd(&sg[qq*2+1],ps[1]); atomicAdd(&qg[qq*2+1],pq[1]);
  }
  __syncthreads();
  if(tid<8){
    atomicAdd(&stp[(b*8+tid)*2+0], sg[tid]);
    atomicAdd(&stp[(b*8+tid)*2+1], qg[tid]);
  }
}

// ------- devoxelize + GN finalize + affine + swish + add; coalesced out -------
__global__ void k_fuse(const short* __restrict__ grid, const float* __restrict__ nc,
                       const float* __restrict__ py, const float* __restrict__ stp,
                       const float* __restrict__ gg, const float* __restrict__ gb,
                       float* __restrict__ out){
  __shared__ float ot[64][65];
  __shared__ float gmu[8], grs[8];
  int tid=threadIdx.x;
  int blk=blockIdx.x;
  int b=blk>>6, n0=(blk&63)*64;
  int nl=tid>>2, qq=tid&3;
  int n=n0+nl;

  if(tid<8){
    float s=stp[(b*8+tid)*2+0], q=stp[(b*8+tid)*2+1];
    float mu=s/(8.f*NP);
    float var=q/(8.f*NP)-mu*mu;
    gmu[tid]=mu;
    grs[tid]=1.0f/sqrtf(var+GNEPS);
  }
  __syncthreads();

  float d_[3]; int i0[3], i1[3];
  #pragma unroll
  for(int dd=0;dd<3;dd++){
    float c=nc[(b*3+dd)*NP+n];
    c=fminf(fmaxf(c,0.f),31.f);
    float f=floorf(c);
    d_[dd]=c-f;
    i0[dd]=(int)f;
    i1[dd]=min(i0[dd]+1,31);
  }
  int idx8[8]; float w8[8];
  #pragma unroll
  for(int k=0;k<8;k++){
    int xx=(k&4)?i1[0]:i0[0];
    int yy=(k&2)?i1[1]:i0[1];
    int zz=(k&1)?i1[2]:i0[2];
    float wx=(k&4)?d_[0]:(1.f-d_[0]);
    float wy=(k&2)?d_[1]:(1.f-d_[1]);
    float wz=(k&1)?d_[2]:(1.f-d_[2]);
    idx8[k]=xx*1024+yy*32+zz;
    w8[k]=wx*wy*wz;
  }
  const short* gbase = grid + (size_t)b*R3*CH;
  #pragma unroll
  for(int c8=0;c8<2;c8++){
    int c0=qq*16+c8*8;
    float dv[8]={0.f,0.f,0.f,0.f,0.f,0.f,0.f,0.f};
    #pragma unroll
    for(int k=0;k<8;k++){
      short8 gv=*(const short8*)(gbase + (size_t)idx8[k]*CH + c0);
      #pragma unroll
      for(int j=0;j<8;j++) dv[j]+=w8[k]*bf2f(gv[j]);
    }
    #pragma unroll
    for(int j=0;j<8;j++){
      int c=c0+j;
      float yn=(py[(size_t)(b*CH+c)*NP+n]-gmu[c>>3])*grs[c>>3]*gg[c]+gb[c];
      float sw=yn/(1.f+expf(-yn));
      ot[c][nl]=dv[j]+sw;
    }
  }
  __syncthreads();
  for(int i=tid;i<1024;i+=256){
    int c=i>>4, sg=i&15;
    float4_ v={ot[c][sg*4+0],ot[c][sg*4+1],ot[c][sg*4+2],ot[c][sg*4+3]};
    *(float4_*)(out + (size_t)(b*CH+c)*NP + n0 + sg*4) = v;
  }
}

// ---------------- merged passthrough copy (coords + temb) ----------------
__global__ void k_copyall(const float* __restrict__ coords, const float* __restrict__ temb,
                          float* __restrict__ out){
  int t=blockIdx.x*256+threadIdx.x;
  if(t<98304) out[2097152+t]=coords[t];
  else if(t<98816) out[2195456+(t-98304)]=temb[t-98304];
}

extern "C" void kernel_launch(void* const* d_in, const int* in_sizes, int n_in,
                              void* d_out, int out_size, void* d_ws, size_t ws_size,
                              hipStream_t stream){
  const float* features=(const float*)d_in[0];
  const float* coords  =(const float*)d_in[1];
  const float* temb    =(const float*)d_in[2];
  const float* c1w=(const float*)d_in[3];
  const float* c1b=(const float*)d_in[4];
  const float* b1g=(const float*)d_in[5];
  const float* b1b=(const float*)d_in[6];
  const float* b1m=(const float*)d_in[7];
  const float* b1v=(const float*)d_in[8];
  const float* c2w=(const float*)d_in[9];
  const float* c2b=(const float*)d_in[10];
  const float* b2g=(const float*)d_in[11];
  const float* b2b=(const float*)d_in[12];
  const float* b2m=(const float*)d_in[13];
  const float* b2v=(const float*)d_in[14];
  const float* pfw=(const float*)d_in[15];
  const float* pfb=(const float*)d_in[16];
  const float* gng=(const float*)d_in[17];
  const float* gnb=(const float*)d_in[18];

  float* F=(float*)d_ws;
  float* ms  = F + 0;                   // 32
  float* nc  = F + 32;                  // 98304
  int*   vi  = (int*)(F + 98336);       // 32768
  short* w1t = (short*)(F + 131104);    // 110592 sh = 55296 f
  short* w2t = (short*)(F + 186400);    // 55296 f
  float* py  = F + 241696;              // 2097152
  float* stp = F + 2338848;             // 128  (memset start)
  float* cnt = F + 2338976;             // 262144
  float* gA  = F + 2601120;             // 16777216
  short* gBF1= (short*)(F + 19378336);  // 16777216 sh = 8388608 f
  short* gBF2= (short*)(F + 27766944);  // 8388608 f
  float* out=(float*)d_out;

  hipMemsetAsync(stp, 0, (size_t)(128+262144+16777216)*4, stream);

  k_voxstats<<<8,256,0,stream>>>(coords, ms);
  k_assign  <<<128,256,0,stream>>>(coords, ms, nc, vi);
  k_scatter <<<8192,256,0,stream>>>(features, vi, gA, cnt);
  k_gridmean<<<8192,256,0,stream>>>(gA, cnt, gBF1);
  k_wt3x2   <<<864,256,0,stream>>>(c1w, c2w, w1t, w2t);
  k_conv_mfma<<<1024,256,0,stream>>>(gBF1, gBF2, w1t, c1b, b1g, b1b, b1m, b1v);
  k_conv_mfma<<<1024,256,0,stream>>>(gBF2, gBF1, w2t, c2b, b2g, b2b, b2m, b2v);
  k_ptgemm  <<<512,256,0,stream>>>(features, pfw, pfb, py, stp);
  k_fuse    <<<512,256,0,stream>>>(gBF1, nc, py, stp, gng, gnb, out);
  k_copyall <<<386,256,0,stream>>>(coords, temb, out);
}